// Round 19
// baseline (430.373 us; speedup 1.0000x reference)
//
#include <hip/hip_runtime.h>
#include <hip/hip_bf16.h>
#include <math.h>

#define BSZ 8
#define SEQ 1024
#define EMB 512
#define NH 8
#define HD 64
#define UE 6
#define QKSCALE 0.125f

typedef unsigned short u16;
typedef short bf16x8 __attribute__((ext_vector_type(8)));
typedef float f32x4 __attribute__((ext_vector_type(4)));
typedef unsigned short ushort4_t __attribute__((ext_vector_type(4)));

__device__ __forceinline__ u16 f2bf(float f) {
  unsigned u = __float_as_uint(f);
  unsigned r = (u + 0x7fffu + ((u >> 16) & 1u)) >> 16;
  return (u16)r;
}
__device__ __forceinline__ float bf2f(u16 v) {
  return __uint_as_float(((unsigned)v) << 16);
}
__device__ __forceinline__ void f2hl(float f, u16& hi, u16& lo) {
  hi = f2bf(f);
  float fh = __uint_as_float(((unsigned)hi) << 16);
  lo = f2bf(f - fh);
}
#define F2HL_V(fv, hv, lv, idx)            \
  {                                        \
    u16 _h, _l;                            \
    f2hl((fv), _h, _l);                    \
    (hv)[idx] = (short)_h;                 \
    (lv)[idx] = (short)_l;                 \
  }
__device__ __forceinline__ f32x4 mfma_bf16(bf16x8 a, bf16x8 b, f32x4 c) {
  return __builtin_amdgcn_mfma_f32_16x16x32_bf16(a, b, c, 0, 0, 0);
}

// ---------------- K0a: split f32 -> (hi,lo) bf16 (single tensor) ----------------
__global__ __launch_bounds__(256) void split_kernel(const float* __restrict__ src,
                                                    u16* __restrict__ hi, u16* __restrict__ lo, int n4) {
  int i = blockIdx.x * 256 + threadIdx.x;
  if (i >= n4) return;
  float4 v = ((const float4*)src)[i];
  ushort4_t h, l;
  F2HL_V(v.x, h, l, 0); F2HL_V(v.y, h, l, 1);
  F2HL_V(v.z, h, l, 2); F2HL_V(v.w, h, l, 3);
  ((ushort4_t*)hi)[i] = h;
  ((ushort4_t*)lo)[i] = l;
}

// ---------------- K0b: split all 4 weight matrices in ONE launch ----------------
__global__ __launch_bounds__(256) void split4_kernel(
    const float* __restrict__ s0, const float* __restrict__ s1,
    const float* __restrict__ s2, const float* __restrict__ s3,
    u16* __restrict__ Wsp, int n4) {
  const int y = blockIdx.y;
  const float* src = (y == 0) ? s0 : (y == 1) ? s1 : (y == 2) ? s2 : s3;
  u16* hi = Wsp + (size_t)y * 524288;
  u16* lo = hi + 262144;
  int i = blockIdx.x * 256 + threadIdx.x;
  if (i >= n4) return;
  float4 v = ((const float4*)src)[i];
  ushort4_t h, l;
  F2HL_V(v.x, h, l, 0); F2HL_V(v.y, h, l, 1);
  F2HL_V(v.z, h, l, 2); F2HL_V(v.w, h, l, 3);
  ((ushort4_t*)hi)[i] = h;
  ((ushort4_t*)lo)[i] = l;
}

// ---------------- K1: QKV projection (bf16x3 MFMA, presplit x) ----------------
__global__ __launch_bounds__(256, 2) void qkv_mfma_kernel(
    const u16* __restrict__ Xhi, const u16* __restrict__ Xlo, const u16* __restrict__ Wsp,
    u16* __restrict__ Qhi, u16* __restrict__ Qlo,
    u16* __restrict__ Khi, u16* __restrict__ Klo, u16* __restrict__ Vt) {
  const int mt = blockIdx.x, h = blockIdx.y, wsel = blockIdx.z;
  const int m0 = mt * 64, c0 = h * 64;
  const u16* __restrict__ WH = Wsp + (size_t)wsel * 524288;
  const u16* __restrict__ WL = WH + 262144;
  __shared__ u16 AH[64][40], AL[64][40], BH[64][40], BL[64][40];
  __shared__ u16 vout[64][69];
  const int t = threadIdx.x, w = t >> 6, l = t & 63;
  const int wr = (w >> 1) * 32, wc = (w & 1) * 32;
  f32x4 acc[2][2] = {};
  const int srow = t >> 2;
  for (int e0 = 0; e0 < EMB; e0 += 32) {
    {
      const int c = (t & 3) * 8;
      *(bf16x8*)&AH[srow][c] = *(const bf16x8*)&Xhi[(size_t)(m0 + srow) * EMB + e0 + c];
      *(bf16x8*)&AL[srow][c] = *(const bf16x8*)&Xlo[(size_t)(m0 + srow) * EMB + e0 + c];
      *(bf16x8*)&BH[srow][c] = *(const bf16x8*)&WH[(size_t)(c0 + srow) * EMB + e0 + c];
      *(bf16x8*)&BL[srow][c] = *(const bf16x8*)&WL[(size_t)(c0 + srow) * EMB + e0 + c];
    }
    __syncthreads();
    const int ar = l & 15, ach = (l >> 4) << 3;
    bf16x8 ah0 = *(bf16x8*)&AH[wr + ar][ach],      ah1 = *(bf16x8*)&AH[wr + 16 + ar][ach];
    bf16x8 al0 = *(bf16x8*)&AL[wr + ar][ach],      al1 = *(bf16x8*)&AL[wr + 16 + ar][ach];
    bf16x8 bh0 = *(bf16x8*)&BH[wc + ar][ach],      bh1 = *(bf16x8*)&BH[wc + 16 + ar][ach];
    bf16x8 bl0 = *(bf16x8*)&BL[wc + ar][ach],      bl1 = *(bf16x8*)&BL[wc + 16 + ar][ach];
    acc[0][0] = mfma_bf16(ah0, bh0, acc[0][0]); acc[0][0] = mfma_bf16(ah0, bl0, acc[0][0]); acc[0][0] = mfma_bf16(al0, bh0, acc[0][0]);
    acc[0][1] = mfma_bf16(ah0, bh1, acc[0][1]); acc[0][1] = mfma_bf16(ah0, bl1, acc[0][1]); acc[0][1] = mfma_bf16(al0, bh1, acc[0][1]);
    acc[1][0] = mfma_bf16(ah1, bh0, acc[1][0]); acc[1][0] = mfma_bf16(ah1, bl0, acc[1][0]); acc[1][0] = mfma_bf16(al1, bh0, acc[1][0]);
    acc[1][1] = mfma_bf16(ah1, bh1, acc[1][1]); acc[1][1] = mfma_bf16(ah1, bl1, acc[1][1]); acc[1][1] = mfma_bf16(al1, bh1, acc[1][1]);
    __syncthreads();
  }
  const int bb = m0 >> 10, n0 = m0 & 1023;
  if (wsel < 2) {
    u16* __restrict__ OH = wsel ? Khi : Qhi;
    u16* __restrict__ OL = wsel ? Klo : Qlo;
#pragma unroll
    for (int i = 0; i < 2; ++i)
#pragma unroll
      for (int j = 0; j < 2; ++j) {
        const int col = wc + 16 * j + (l & 15);
#pragma unroll
        for (int r = 0; r < 4; ++r) {
          const int n = n0 + wr + 16 * i + ((l >> 4) << 2) + r;
          size_t o = ((size_t)(bb * NH + h) * SEQ + n) * HD + col;
          u16 hi, lo; f2hl(acc[i][j][r], hi, lo);
          OH[o] = hi; OL[o] = lo;
        }
      }
  } else {
#pragma unroll
    for (int i = 0; i < 2; ++i)
#pragma unroll
      for (int j = 0; j < 2; ++j) {
        const int col = wc + 16 * j + (l & 15);
#pragma unroll
        for (int r = 0; r < 4; ++r)
          vout[wr + 16 * i + ((l >> 4) << 2) + r][col] = f2bf(acc[i][j][r]);
      }
    __syncthreads();
    const int d = t >> 2, nch = (t & 3) * 16;
    bf16x8 o0, o1;
#pragma unroll
    for (int i = 0; i < 8; ++i) o0[i] = (short)vout[nch + i][d];
#pragma unroll
    for (int i = 0; i < 8; ++i) o1[i] = (short)vout[nch + 8 + i][d];
    size_t dst = ((size_t)(bb * NH + h) * HD + d) * SEQ + n0 + nch;
    *(bf16x8*)&Vt[dst] = o0;
    *(bf16x8*)&Vt[dst + 8] = o1;
  }
}

// ---------------- K2: bf16 exp-scores + per-(row,ktile) sums ----------------
// R18 core + Q/Wu/bu prefetch one head-pair ahead (mirrors the K prefetch):
// removes the exposed L2 latency of Q loads from the per-hp critical path.
__global__ __launch_bounds__(256, 2) void scores_kernel(
    const u16* __restrict__ Qhi, const u16* __restrict__ Qlo,
    const u16* __restrict__ Khi, const u16* __restrict__ Klo,
    const float* __restrict__ u, const int* __restrict__ umask,
    const float* __restrict__ Wu, const float* __restrict__ bu,
    u16* __restrict__ praw, float* __restrict__ sums) {
  const int kt = blockIdx.x, qt = blockIdx.y, b = blockIdx.z;
  const int q0 = qt * 64, k0 = kt * 64;
  __shared__ u16 KsH[2][64][68], KsL[2][64][68];
  __shared__ unsigned char ms[64][68];
  __shared__ u16 TrB[4][2][16][72];  // [wave][head][qrow][col] bf16 exp values
  const int t = threadIdx.x, w = t >> 6, l = t & 63;
  const int kl = l & 15, g = l >> 4;
  const int qb = 16 * w + (g << 2);

#pragma unroll
  for (int r = 0; r < 16; ++r) {
    int idx = r * 256 + t; int k = idx >> 6, q = idx & 63;
    ms[k][q] = (unsigned char)(umask[((size_t)b * SEQ + k0 + k) * SEQ + q0 + q] != 0);
  }

  const float* ubase = u + ((size_t)b * UE * SEQ + q0 + qb) * SEQ + k0 + kl;

  const int krow_s = t >> 2, kc_s = (t & 3) * 16;
  bf16x8 preH[2][2], preL[2][2];
#pragma unroll
  for (int h2 = 0; h2 < 2; ++h2) {
    const u16* kp = Khi + ((size_t)(b * NH + h2) * SEQ + k0 + krow_s) * HD + kc_s;
    const u16* kq = Klo + ((size_t)(b * NH + h2) * SEQ + k0 + krow_s) * HD + kc_s;
    preH[h2][0] = *(const bf16x8*)kp; preH[h2][1] = *(const bf16x8*)(kp + 8);
    preL[h2][0] = *(const bf16x8*)kq; preL[h2][1] = *(const bf16x8*)(kq + 8);
  }

  // Q / Wu / bu prefetch for head-pair 0
  bf16x8 qpreH[2][2], qpreL[2][2];
  float wupre[2][UE], bupre[2];
#pragma unroll
  for (int h2 = 0; h2 < 2; ++h2) {
    const int bh = b * NH + h2;
    const u16* qp = Qhi + ((size_t)bh * SEQ + q0 + 16 * w + kl) * HD + (g << 3);
    const u16* qq = Qlo + ((size_t)bh * SEQ + q0 + 16 * w + kl) * HD + (g << 3);
    qpreH[h2][0] = *(const bf16x8*)qp; qpreH[h2][1] = *(const bf16x8*)(qp + 32);
    qpreL[h2][0] = *(const bf16x8*)qq; qpreL[h2][1] = *(const bf16x8*)(qq + 32);
#pragma unroll
    for (int uu = 0; uu < UE; ++uu) wupre[h2][uu] = Wu[h2 * UE + uu];
    bupre[h2] = bu[h2];
  }

  // flush lane mapping: row rr of this wave's 16 q-rows, 16-col group cg
  const int rr = l >> 2, cg = (l & 3) * 16;

  for (int hp = 0; hp < 4; ++hp) {
    const int h0 = hp * 2;
    __syncthreads();
#pragma unroll
    for (int h2 = 0; h2 < 2; ++h2) {
      *(bf16x8*)&KsH[h2][krow_s][kc_s] = preH[h2][0];
      *(bf16x8*)&KsH[h2][krow_s][kc_s + 8] = preH[h2][1];
      *(bf16x8*)&KsL[h2][krow_s][kc_s] = preL[h2][0];
      *(bf16x8*)&KsL[h2][krow_s][kc_s + 8] = preL[h2][1];
    }
    if (hp < 3) {
#pragma unroll
      for (int h2 = 0; h2 < 2; ++h2) {
        const u16* kp = Khi + ((size_t)(b * NH + h0 + 2 + h2) * SEQ + k0 + krow_s) * HD + kc_s;
        const u16* kq = Klo + ((size_t)(b * NH + h0 + 2 + h2) * SEQ + k0 + krow_s) * HD + kc_s;
        preH[h2][0] = *(const bf16x8*)kp; preH[h2][1] = *(const bf16x8*)(kp + 8);
        preL[h2][0] = *(const bf16x8*)kq; preL[h2][1] = *(const bf16x8*)(kq + 8);
      }
    }
    __syncthreads();

    // consume current pair's prefetched Q / consts
    bf16x8 qh[2][2], qo[2][2];
    float wu_[2][UE], bub[2];
#pragma unroll
    for (int h2 = 0; h2 < 2; ++h2) {
      qh[h2][0] = qpreH[h2][0]; qh[h2][1] = qpreH[h2][1];
      qo[h2][0] = qpreL[h2][0]; qo[h2][1] = qpreL[h2][1];
#pragma unroll
      for (int uu = 0; uu < UE; ++uu) wu_[h2][uu] = wupre[h2][uu];
      bub[h2] = bupre[h2];
    }
    // issue next pair's Q / consts: drains under this pair's MFMA+exp phase
    if (hp < 3) {
#pragma unroll
      for (int h2 = 0; h2 < 2; ++h2) {
        const int bh = b * NH + h0 + 2 + h2;
        const u16* qp = Qhi + ((size_t)bh * SEQ + q0 + 16 * w + kl) * HD + (g << 3);
        const u16* qq = Qlo + ((size_t)bh * SEQ + q0 + 16 * w + kl) * HD + (g << 3);
        qpreH[h2][0] = *(const bf16x8*)qp; qpreH[h2][1] = *(const bf16x8*)(qp + 32);
        qpreL[h2][0] = *(const bf16x8*)qq; qpreL[h2][1] = *(const bf16x8*)(qq + 32);
#pragma unroll
        for (int uu = 0; uu < UE; ++uu) wupre[h2][uu] = Wu[(h0 + 2 + h2) * UE + uu];
        bupre[h2] = bu[h0 + 2 + h2];
      }
    }

    float esum[2][4] = {};
#pragma unroll
    for (int tt = 0; tt < 4; ++tt) {
      float uf[UE][2][2];
#pragma unroll
      for (int uu = 0; uu < UE; ++uu)
#pragma unroll
        for (int p = 0; p < 2; ++p) {
          const float* up = ubase + (size_t)uu * SEQ * SEQ + (size_t)(2 * p) * SEQ + 16 * tt;
          uf[uu][p][0] = up[0];
          uf[uu][p][1] = up[SEQ];
        }
      const int krow = tt * 16 + kl, kch = g << 3;
      bf16x8 kh00 = *(bf16x8*)&KsH[0][krow][kch], kh01 = *(bf16x8*)&KsH[0][krow][kch + 32];
      bf16x8 kb00 = *(bf16x8*)&KsL[0][krow][kch], kb01 = *(bf16x8*)&KsL[0][krow][kch + 32];
      bf16x8 kh10 = *(bf16x8*)&KsH[1][krow][kch], kh11 = *(bf16x8*)&KsH[1][krow][kch + 32];
      bf16x8 kb10 = *(bf16x8*)&KsL[1][krow][kch], kb11 = *(bf16x8*)&KsL[1][krow][kch + 32];
      f32x4 a0 = {0.f, 0.f, 0.f, 0.f}, a1 = {0.f, 0.f, 0.f, 0.f};
      a0 = mfma_bf16(qh[0][0], kh00, a0);  a1 = mfma_bf16(qh[1][0], kh10, a1);
      a0 = mfma_bf16(qh[0][1], kh01, a0);  a1 = mfma_bf16(qh[1][1], kh11, a1);
      a0 = mfma_bf16(qh[0][0], kb00, a0);  a1 = mfma_bf16(qh[1][0], kb10, a1);
      a0 = mfma_bf16(qh[0][1], kb01, a0);  a1 = mfma_bf16(qh[1][1], kb11, a1);
      a0 = mfma_bf16(qo[0][0], kh00, a0);  a1 = mfma_bf16(qo[1][0], kh10, a1);
      a0 = mfma_bf16(qo[0][1], kh01, a0);  a1 = mfma_bf16(qo[1][1], kh11, a1);
#pragma unroll
      for (int p = 0; p < 2; ++p) {
        float ub0x = bub[0], ub0y = bub[0], ub1x = bub[1], ub1y = bub[1];
#pragma unroll
        for (int uu = 0; uu < UE; ++uu) {
          const float flo = uf[uu][p][0];
          const float fhi = uf[uu][p][1];
          ub0x = fmaf(wu_[0][uu], flo, ub0x); ub0y = fmaf(wu_[0][uu], fhi, ub0y);
          ub1x = fmaf(wu_[1][uu], flo, ub1x); ub1y = fmaf(wu_[1][uu], fhi, ub1y);
        }
        const unsigned char m0 = ms[tt * 16 + kl][qb + 2 * p];
        const unsigned char m1 = ms[tt * 16 + kl][qb + 2 * p + 1];
        u16 e00 = m0 ? (u16)0 : f2bf(__expf(a0[2 * p] * QKSCALE + ub0x));
        u16 e01 = m1 ? (u16)0 : f2bf(__expf(a0[2 * p + 1] * QKSCALE + ub0y));
        u16 e10 = m0 ? (u16)0 : f2bf(__expf(a1[2 * p] * QKSCALE + ub1x));
        u16 e11 = m1 ? (u16)0 : f2bf(__expf(a1[2 * p + 1] * QKSCALE + ub1y));
        TrB[w][0][(g << 2) + 2 * p][tt * 16 + kl]     = e00;
        TrB[w][0][(g << 2) + 2 * p + 1][tt * 16 + kl] = e01;
        TrB[w][1][(g << 2) + 2 * p][tt * 16 + kl]     = e10;
        TrB[w][1][(g << 2) + 2 * p + 1][tt * 16 + kl] = e11;
        esum[0][2 * p]     += bf2f(e00);
        esum[0][2 * p + 1] += bf2f(e01);
        esum[1][2 * p]     += bf2f(e10);
        esum[1][2 * p + 1] += bf2f(e11);
      }
    }
    // same-wave flush: 2x bf16x8 per head -> full 64B lines (4 lanes/line)
#pragma unroll
    for (int h2 = 0; h2 < 2; ++h2) {
      bf16x8 v0 = *(bf16x8*)&TrB[w][h2][rr][cg];
      bf16x8 v1 = *(bf16x8*)&TrB[w][h2][rr][cg + 8];
      u16* pp = praw + ((size_t)((b * NH + h0 + h2) * SEQ + q0 + 16 * w + rr)) * 2048 + 1024 + k0 + cg;
      *(bf16x8*)pp = v0;
      *(bf16x8*)(pp + 8) = v1;
    }
#pragma unroll
    for (int h2 = 0; h2 < 2; ++h2)
#pragma unroll
      for (int r = 0; r < 4; ++r) {
#pragma unroll
        for (int o = 1; o <= 8; o <<= 1) esum[h2][r] += __shfl_xor(esum[h2][r], o);
      }
    if (kl == 0) {
#pragma unroll
      for (int h2 = 0; h2 < 2; ++h2)
#pragma unroll
        for (int r = 0; r < 4; ++r)
          sums[((size_t)(b * NH + h0 + h2) * SEQ + q0 + qb + r) * 16 + kt] = esum[h2][r];
    }
  }
}

// ---------------- K3: normalize-write + PV (bf16 praw, no exp) ----------------
__global__ __launch_bounds__(256, 4) void pv_softmax_kernel(
    float* attn, const u16* __restrict__ Vt,
    const float* __restrict__ sums, u16* __restrict__ ctx) {
  const int qt = blockIdx.x, bh = blockIdx.y;
  const int q0 = qt * 64;
  __shared__ u16 Pl[64][72], Vs[64][72];
  __shared__ float invl[64];
  const int t = threadIdx.x, w = t >> 6, l = t & 63;
  const int row = t >> 2, cc = (t & 3) * 16;

  float S = 0.f;
  {
    const float* sp = sums + ((size_t)bh * SEQ + q0 + row) * 16 + (t & 3) * 4;
#pragma unroll
    for (int j = 0; j < 4; ++j) S += sp[j];
#pragma unroll
    for (int o = 1; o <= 2; o <<= 1) S += __shfl_xor(S, o);
  }
  const float inv = 1.0f / S;
  if ((t & 3) == 0) invl[row] = inv;

  const u16* prow = (const u16*)attn + ((size_t)(bh * SEQ + q0 + row)) * 2048 + 1024;
  float* arow = attn + ((size_t)(bh * SEQ + q0 + row)) * SEQ;
  const u16* vrow = Vt + ((size_t)bh * HD + row) * SEQ + cc;

  const int wr = (w >> 1) * 32, wc = (w & 1) * 32;
  f32x4 acc[2][2] = {};
  bf16x8 pa = *(const bf16x8*)&prow[cc], pb = *(const bf16x8*)&prow[cc + 8];
  bf16x8 vb0 = *(const bf16x8*)vrow, vb1 = *(const bf16x8*)(vrow + 8);

  for (int k0 = 0; k0 < SEQ; k0 += 64) {
    float* ap = arow + k0 + cc;
    {
      float4 o0, o1, o2, o3;
      o0.x = bf2f((u16)pa[0]) * inv; o0.y = bf2f((u16)pa[1]) * inv;
      o0.z = bf2f((u16)pa[2]) * inv; o0.w = bf2f((u16)pa[3]) * inv;
      o1.x = bf2f((u16)pa[4]) * inv; o1.y = bf2f((u16)pa[5]) * inv;
      o1.z = bf2f((u16)pa[6]) * inv; o1.w = bf2f((u16)pa[7]) * inv;
      o2.x = bf2f((u16)pb[0]) * inv; o2.y = bf2f((u16)pb[1]) * inv;
      o2.z = bf2f((u16)pb[2]) * inv; o2.w = bf2f((u16)pb[3]) * inv;
      o3.x = bf2f((u16)pb[4]) * inv; o3.y = bf2f((u16)pb[5]) * inv;
      o3.z = bf2f((u16)pb[6]) * inv; o3.w = bf2f((u16)pb[7]) * inv;
      ((float4*)ap)[0] = o0; ((float4*)ap)[1] = o1;
      ((float4*)ap)[2] = o2; ((float4*)ap)[3] = o3;
    }
    *(bf16x8*)&Pl[row][cc] = pa;
    *(bf16x8*)&Pl[row][cc + 8] = pb;
    *(bf16x8*)&Vs[row][cc] = vb0;
    *(bf16x8*)&Vs[row][cc + 8] = vb1;

    if (k0 + 64 < SEQ) {
      pa = *(const bf16x8*)&prow[k0 + 64 + cc];
      pb = *(const bf16x8*)&prow[k0 + 64 + cc + 8];
      vb0 = *(const bf16x8*)(vrow + k0 + 64);
      vb1 = *(const bf16x8*)(vrow + k0 + 72);
    }
    __syncthreads();
#pragma unroll
    for (int kb = 0; kb < 2; ++kb) {
      const int kch = kb * 32 + ((l >> 4) << 3);
      bf16x8 a0 = *(bf16x8*)&Pl[wr + (l & 15)][kch];
      bf16x8 a1 = *(bf16x8*)&Pl[wr + 16 + (l & 15)][kch];
      bf16x8 b0 = *(bf16x8*)&Vs[wc + (l & 15)][kch];
      bf16x8 b1 = *(bf16x8*)&Vs[wc + 16 + (l & 15)][kch];
      acc[0][0] = mfma_bf16(a0, b0, acc[0][0]);
      acc[0][1] = mfma_bf16(a0, b1, acc[0][1]);
      acc[1][0] = mfma_bf16(a1, b0, acc[1][0]);
      acc[1][1] = mfma_bf16(a1, b1, acc[1][1]);
    }
    __syncthreads();
  }
  const int b = bh >> 3, h = bh & 7;
#pragma unroll
  for (int i = 0; i < 2; ++i)
#pragma unroll
    for (int j = 0; j < 2; ++j) {
      const int d = h * HD + wc + 16 * j + (l & 15);
#pragma unroll
      for (int r = 0; r < 4; ++r) {
        const int ql_ = wr + 16 * i + ((l >> 4) << 2) + r;
        ctx[((size_t)(b * SEQ + q0 + ql_)) * EMB + d] = f2bf(acc[i][j][r] * invl[ql_]);
      }
    }
}

// ---------------- K4: out = ctx(bf16) @ Wo^T(hi/lo) + bo ----------------
__global__ __launch_bounds__(256, 2) void oproj_kernel(
    const u16* __restrict__ ctx,
    const u16* __restrict__ WoH, const u16* __restrict__ WoL,
    const float* __restrict__ bo, float* __restrict__ out) {
  const int mt = blockIdx.x, ct = blockIdx.y;
  const int m0 = mt * 64, c0 = ct * 64;
  __shared__ u16 AH[64][40], BH[64][40], BL[64][40];
  const int t = threadIdx.x, w = t >> 6, l = t & 63;
  const int wr = (w >> 1) * 32, wc = (w & 1) * 32;
  f32x4 acc[2][2] = {};
  const int srow = t >> 2, sc = (t & 3) * 8;
  for (int e0 = 0; e0 < EMB; e0 += 32) {
    *(bf16x8*)&AH[srow][sc] = *(const bf16x8*)&ctx[(size_t)(m0 + srow) * EMB + e0 + sc];
    *(bf16x8*)&BH[srow][sc] = *(const bf16x8*)&WoH[(size_t)(c0 + srow) * EMB + e0 + sc];
    *(bf16x8*)&BL[srow][sc] = *(const bf16x8*)&WoL[(size_t)(c0 + srow) * EMB + e0 + sc];
    __syncthreads();
    const int ar = l & 15, ach = (l >> 4) << 3;
    bf16x8 ah0 = *(bf16x8*)&AH[wr + ar][ach],      ah1 = *(bf16x8*)&AH[wr + 16 + ar][ach];
    bf16x8 bh0 = *(bf16x8*)&BH[wc + ar][ach],      bh1 = *(bf16x8*)&BH[wc + 16 + ar][ach];
    bf16x8 bl0 = *(bf16x8*)&BL[wc + ar][ach],      bl1 = *(bf16x8*)&BL[wc + 16 + ar][ach];
    acc[0][0] = mfma_bf16(ah0, bh0, acc[0][0]); acc[0][0] = mfma_bf16(ah0, bl0, acc[0][0]);
    acc[0][1] = mfma_bf16(ah0, bh1, acc[0][1]); acc[0][1] = mfma_bf16(ah0, bl1, acc[0][1]);
    acc[1][0] = mfma_bf16(ah1, bh0, acc[1][0]); acc[1][0] = mfma_bf16(ah1, bl0, acc[1][0]);
    acc[1][1] = mfma_bf16(ah1, bh1, acc[1][1]); acc[1][1] = mfma_bf16(ah1, bl1, acc[1][1]);
    __syncthreads();
  }
#pragma unroll
  for (int i = 0; i < 2; ++i)
#pragma unroll
    for (int j = 0; j < 2; ++j) {
      const int col = c0 + wc + 16 * j + (l & 15);
      const float bias = bo[col];
#pragma unroll
      for (int r = 0; r < 4; ++r) {
        const int m = m0 + wr + 16 * i + ((l >> 4) << 2) + r;
        out[(size_t)m * EMB + col] = acc[i][j][r] + bias;
      }
    }
}

extern "C" void kernel_launch(void* const* d_in, const int* in_sizes, int n_in,
                              void* d_out, int out_size, void* d_ws, size_t ws_size,
                              hipStream_t stream) {
  const float* x = (const float*)d_in[0];
  const float* u = (const float*)d_in[1];
  const int* umask = (const int*)d_in[2];
  const float* Wq = (const float*)d_in[3];
  const float* Wk = (const float*)d_in[4];
  const float* Wv = (const float*)d_in[5];
  const float* Wu = (const float*)d_in[6];
  const float* bu = (const float*)d_in[7];
  const float* Wo = (const float*)d_in[8];
  const float* bo = (const float*)d_in[9];

  float* out = (float*)d_out;
  float* attn = out + (size_t)BSZ * SEQ * EMB;

  const size_t per = (size_t)BSZ * NH * SEQ * HD;  // 4,194,304
  u16* ws = (u16*)d_ws;
  u16* Qhi = ws;
  u16* Qlo = Qhi + per;
  u16* Khi = Qlo + per;
  u16* Klo = Khi + per;
  u16* Vt = Klo + per;
  u16* ctx = Vt + per;
  float* sums = (float*)(ctx + per);               // 4.19MB
  u16* Wsp = (u16*)(sums + (size_t)BSZ * NH * SEQ * 16);
  // ws total: 58.7 MB (proven envelope)

  u16* Xhi = (u16*)attn;
  u16* Xlo = Xhi + (size_t)BSZ * SEQ * EMB;

  const int wn4 = 262144 / 4;
  split4_kernel<<<dim3(wn4 / 256, 4), 256, 0, stream>>>(Wq, Wk, Wv, Wo, Wsp, wn4);
  const int xn4 = (int)((size_t)BSZ * SEQ * EMB / 4);  // 1,048,576
  split_kernel<<<dim3(xn4 / 256), 256, 0, stream>>>(x, Xhi, Xlo, xn4);

  qkv_mfma_kernel<<<dim3(128, 8, 3), 256, 0, stream>>>(Xhi, Xlo, Wsp, Qhi, Qlo, Khi, Klo, Vt);
  scores_kernel<<<dim3(16, 16, 8), 256, 0, stream>>>(Qhi, Qlo, Khi, Klo, u, umask, Wu, bu,
                                                     (u16*)attn, sums);
  pv_softmax_kernel<<<dim3(16, 64), 256, 0, stream>>>(attn, Vt, sums, ctx);
  oproj_kernel<<<dim3(128, 8), 256, 0, stream>>>(ctx, Wsp + 3 * 524288, Wsp + 3 * 524288 + 262144, bo, out);
}

// Round 20
// 368.441 us; speedup vs baseline: 1.1681x; 1.1681x over previous
//
#include <hip/hip_runtime.h>
#include <hip/hip_bf16.h>
#include <math.h>

#define BSZ 8
#define SEQ 1024
#define EMB 512
#define NH 8
#define HD 64
#define UE 6
#define QKSCALE 0.125f

typedef unsigned short u16;
typedef short bf16x8 __attribute__((ext_vector_type(8)));
typedef float f32x4 __attribute__((ext_vector_type(4)));
typedef unsigned short ushort4_t __attribute__((ext_vector_type(4)));

__device__ __forceinline__ u16 f2bf(float f) {
  unsigned u = __float_as_uint(f);
  unsigned r = (u + 0x7fffu + ((u >> 16) & 1u)) >> 16;
  return (u16)r;
}
__device__ __forceinline__ float bf2f(u16 v) {
  return __uint_as_float(((unsigned)v) << 16);
}
__device__ __forceinline__ void f2hl(float f, u16& hi, u16& lo) {
  hi = f2bf(f);
  float fh = __uint_as_float(((unsigned)hi) << 16);
  lo = f2bf(f - fh);
}
#define F2HL_V(fv, hv, lv, idx)            \
  {                                        \
    u16 _h, _l;                            \
    f2hl((fv), _h, _l);                    \
    (hv)[idx] = (short)_h;                 \
    (lv)[idx] = (short)_l;                 \
  }
__device__ __forceinline__ f32x4 mfma_bf16(bf16x8 a, bf16x8 b, f32x4 c) {
  return __builtin_amdgcn_mfma_f32_16x16x32_bf16(a, b, c, 0, 0, 0);
}

// ---------------- K0a: split f32 -> (hi,lo) bf16 (single tensor) ----------------
__global__ __launch_bounds__(256) void split_kernel(const float* __restrict__ src,
                                                    u16* __restrict__ hi, u16* __restrict__ lo, int n4) {
  int i = blockIdx.x * 256 + threadIdx.x;
  if (i >= n4) return;
  float4 v = ((const float4*)src)[i];
  ushort4_t h, l;
  F2HL_V(v.x, h, l, 0); F2HL_V(v.y, h, l, 1);
  F2HL_V(v.z, h, l, 2); F2HL_V(v.w, h, l, 3);
  ((ushort4_t*)hi)[i] = h;
  ((ushort4_t*)lo)[i] = l;
}

// ---------------- K0b: split all 4 weight matrices in ONE launch ----------------
__global__ __launch_bounds__(256) void split4_kernel(
    const float* __restrict__ s0, const float* __restrict__ s1,
    const float* __restrict__ s2, const float* __restrict__ s3,
    u16* __restrict__ Wsp, int n4) {
  const int y = blockIdx.y;
  const float* src = (y == 0) ? s0 : (y == 1) ? s1 : (y == 2) ? s2 : s3;
  u16* hi = Wsp + (size_t)y * 524288;
  u16* lo = hi + 262144;
  int i = blockIdx.x * 256 + threadIdx.x;
  if (i >= n4) return;
  float4 v = ((const float4*)src)[i];
  ushort4_t h, l;
  F2HL_V(v.x, h, l, 0); F2HL_V(v.y, h, l, 1);
  F2HL_V(v.z, h, l, 2); F2HL_V(v.w, h, l, 3);
  ((ushort4_t*)hi)[i] = h;
  ((ushort4_t*)lo)[i] = l;
}

// ---------------- K1: QKV projection (bf16x3 MFMA, presplit x) ----------------
__global__ __launch_bounds__(256, 2) void qkv_mfma_kernel(
    const u16* __restrict__ Xhi, const u16* __restrict__ Xlo, const u16* __restrict__ Wsp,
    u16* __restrict__ Qhi, u16* __restrict__ Qlo,
    u16* __restrict__ Khi, u16* __restrict__ Klo, u16* __restrict__ Vt) {
  const int mt = blockIdx.x, h = blockIdx.y, wsel = blockIdx.z;
  const int m0 = mt * 64, c0 = h * 64;
  const u16* __restrict__ WH = Wsp + (size_t)wsel * 524288;
  const u16* __restrict__ WL = WH + 262144;
  __shared__ u16 AH[64][40], AL[64][40], BH[64][40], BL[64][40];
  __shared__ u16 vout[64][69];
  const int t = threadIdx.x, w = t >> 6, l = t & 63;
  const int wr = (w >> 1) * 32, wc = (w & 1) * 32;
  f32x4 acc[2][2] = {};
  const int srow = t >> 2;
  for (int e0 = 0; e0 < EMB; e0 += 32) {
    {
      const int c = (t & 3) * 8;
      *(bf16x8*)&AH[srow][c] = *(const bf16x8*)&Xhi[(size_t)(m0 + srow) * EMB + e0 + c];
      *(bf16x8*)&AL[srow][c] = *(const bf16x8*)&Xlo[(size_t)(m0 + srow) * EMB + e0 + c];
      *(bf16x8*)&BH[srow][c] = *(const bf16x8*)&WH[(size_t)(c0 + srow) * EMB + e0 + c];
      *(bf16x8*)&BL[srow][c] = *(const bf16x8*)&WL[(size_t)(c0 + srow) * EMB + e0 + c];
    }
    __syncthreads();
    const int ar = l & 15, ach = (l >> 4) << 3;
    bf16x8 ah0 = *(bf16x8*)&AH[wr + ar][ach],      ah1 = *(bf16x8*)&AH[wr + 16 + ar][ach];
    bf16x8 al0 = *(bf16x8*)&AL[wr + ar][ach],      al1 = *(bf16x8*)&AL[wr + 16 + ar][ach];
    bf16x8 bh0 = *(bf16x8*)&BH[wc + ar][ach],      bh1 = *(bf16x8*)&BH[wc + 16 + ar][ach];
    bf16x8 bl0 = *(bf16x8*)&BL[wc + ar][ach],      bl1 = *(bf16x8*)&BL[wc + 16 + ar][ach];
    acc[0][0] = mfma_bf16(ah0, bh0, acc[0][0]); acc[0][0] = mfma_bf16(ah0, bl0, acc[0][0]); acc[0][0] = mfma_bf16(al0, bh0, acc[0][0]);
    acc[0][1] = mfma_bf16(ah0, bh1, acc[0][1]); acc[0][1] = mfma_bf16(ah0, bl1, acc[0][1]); acc[0][1] = mfma_bf16(al0, bh1, acc[0][1]);
    acc[1][0] = mfma_bf16(ah1, bh0, acc[1][0]); acc[1][0] = mfma_bf16(ah1, bl0, acc[1][0]); acc[1][0] = mfma_bf16(al1, bh0, acc[1][0]);
    acc[1][1] = mfma_bf16(ah1, bh1, acc[1][1]); acc[1][1] = mfma_bf16(ah1, bl1, acc[1][1]); acc[1][1] = mfma_bf16(al1, bh1, acc[1][1]);
    __syncthreads();
  }
  const int bb = m0 >> 10, n0 = m0 & 1023;
  if (wsel < 2) {
    u16* __restrict__ OH = wsel ? Khi : Qhi;
    u16* __restrict__ OL = wsel ? Klo : Qlo;
#pragma unroll
    for (int i = 0; i < 2; ++i)
#pragma unroll
      for (int j = 0; j < 2; ++j) {
        const int col = wc + 16 * j + (l & 15);
#pragma unroll
        for (int r = 0; r < 4; ++r) {
          const int n = n0 + wr + 16 * i + ((l >> 4) << 2) + r;
          size_t o = ((size_t)(bb * NH + h) * SEQ + n) * HD + col;
          u16 hi, lo; f2hl(acc[i][j][r], hi, lo);
          OH[o] = hi; OL[o] = lo;
        }
      }
  } else {
#pragma unroll
    for (int i = 0; i < 2; ++i)
#pragma unroll
      for (int j = 0; j < 2; ++j) {
        const int col = wc + 16 * j + (l & 15);
#pragma unroll
        for (int r = 0; r < 4; ++r)
          vout[wr + 16 * i + ((l >> 4) << 2) + r][col] = f2bf(acc[i][j][r]);
      }
    __syncthreads();
    const int d = t >> 2, nch = (t & 3) * 16;
    bf16x8 o0, o1;
#pragma unroll
    for (int i = 0; i < 8; ++i) o0[i] = (short)vout[nch + i][d];
#pragma unroll
    for (int i = 0; i < 8; ++i) o1[i] = (short)vout[nch + 8 + i][d];
    size_t dst = ((size_t)(bb * NH + h) * HD + d) * SEQ + n0 + nch;
    *(bf16x8*)&Vt[dst] = o0;
    *(bf16x8*)&Vt[dst + 8] = o1;
  }
}

// ---------------- K2: bf16 exp-scores + per-(row,ktile) sums ----------------
// R15/R18 measured-best core: LDS-staged K pairs, paired-head MFMA ILP, streamed u,
// bf16 praw accumulated in u16 LDS transpose tile, flushed once per head-pair as
// full-line bf16x8 stores into the upper 2KB of each attn row. esum sums the
// bf16-ROUNDED values so pv's normalization matches stored praw exactly.
// NOTE: Q prefetch-ahead was tried (R19) and spills -> keep Q loads in-iteration.
__global__ __launch_bounds__(256, 2) void scores_kernel(
    const u16* __restrict__ Qhi, const u16* __restrict__ Qlo,
    const u16* __restrict__ Khi, const u16* __restrict__ Klo,
    const float* __restrict__ u, const int* __restrict__ umask,
    const float* __restrict__ Wu, const float* __restrict__ bu,
    u16* __restrict__ praw, float* __restrict__ sums) {
  const int kt = blockIdx.x, qt = blockIdx.y, b = blockIdx.z;
  const int q0 = qt * 64, k0 = kt * 64;
  __shared__ u16 KsH[2][64][68], KsL[2][64][68];
  __shared__ unsigned char ms[64][68];
  __shared__ u16 TrB[4][2][16][72];  // [wave][head][qrow][col] bf16 exp values
  const int t = threadIdx.x, w = t >> 6, l = t & 63;
  const int kl = l & 15, g = l >> 4;
  const int qb = 16 * w + (g << 2);

#pragma unroll
  for (int r = 0; r < 16; ++r) {
    int idx = r * 256 + t; int k = idx >> 6, q = idx & 63;
    ms[k][q] = (unsigned char)(umask[((size_t)b * SEQ + k0 + k) * SEQ + q0 + q] != 0);
  }

  const float* ubase = u + ((size_t)b * UE * SEQ + q0 + qb) * SEQ + k0 + kl;

  const int krow_s = t >> 2, kc_s = (t & 3) * 16;
  bf16x8 preH[2][2], preL[2][2];
#pragma unroll
  for (int h2 = 0; h2 < 2; ++h2) {
    const u16* kp = Khi + ((size_t)(b * NH + h2) * SEQ + k0 + krow_s) * HD + kc_s;
    const u16* kq = Klo + ((size_t)(b * NH + h2) * SEQ + k0 + krow_s) * HD + kc_s;
    preH[h2][0] = *(const bf16x8*)kp; preH[h2][1] = *(const bf16x8*)(kp + 8);
    preL[h2][0] = *(const bf16x8*)kq; preL[h2][1] = *(const bf16x8*)(kq + 8);
  }

  // flush lane mapping: row rr of this wave's 16 q-rows, 16-col group cg
  const int rr = l >> 2, cg = (l & 3) * 16;

  for (int hp = 0; hp < 4; ++hp) {
    const int h0 = hp * 2;
    __syncthreads();
#pragma unroll
    for (int h2 = 0; h2 < 2; ++h2) {
      *(bf16x8*)&KsH[h2][krow_s][kc_s] = preH[h2][0];
      *(bf16x8*)&KsH[h2][krow_s][kc_s + 8] = preH[h2][1];
      *(bf16x8*)&KsL[h2][krow_s][kc_s] = preL[h2][0];
      *(bf16x8*)&KsL[h2][krow_s][kc_s + 8] = preL[h2][1];
    }
    if (hp < 3) {
#pragma unroll
      for (int h2 = 0; h2 < 2; ++h2) {
        const u16* kp = Khi + ((size_t)(b * NH + h0 + 2 + h2) * SEQ + k0 + krow_s) * HD + kc_s;
        const u16* kq = Klo + ((size_t)(b * NH + h0 + 2 + h2) * SEQ + k0 + krow_s) * HD + kc_s;
        preH[h2][0] = *(const bf16x8*)kp; preH[h2][1] = *(const bf16x8*)(kp + 8);
        preL[h2][0] = *(const bf16x8*)kq; preL[h2][1] = *(const bf16x8*)(kq + 8);
      }
    }
    __syncthreads();

    bf16x8 qh[2][2], qo[2][2];
    float wu_[2][UE], bub[2];
#pragma unroll
    for (int h2 = 0; h2 < 2; ++h2) {
      const int bh = b * NH + h0 + h2;
      const u16* qp = Qhi + ((size_t)bh * SEQ + q0 + 16 * w + kl) * HD + (g << 3);
      const u16* qq = Qlo + ((size_t)bh * SEQ + q0 + 16 * w + kl) * HD + (g << 3);
      qh[h2][0] = *(const bf16x8*)qp; qh[h2][1] = *(const bf16x8*)(qp + 32);
      qo[h2][0] = *(const bf16x8*)qq; qo[h2][1] = *(const bf16x8*)(qq + 32);
#pragma unroll
      for (int uu = 0; uu < UE; ++uu) wu_[h2][uu] = Wu[(h0 + h2) * UE + uu];
      bub[h2] = bu[h0 + h2];
    }

    float esum[2][4] = {};
#pragma unroll
    for (int tt = 0; tt < 4; ++tt) {
      float uf[UE][2][2];
#pragma unroll
      for (int uu = 0; uu < UE; ++uu)
#pragma unroll
        for (int p = 0; p < 2; ++p) {
          const float* up = ubase + (size_t)uu * SEQ * SEQ + (size_t)(2 * p) * SEQ + 16 * tt;
          uf[uu][p][0] = up[0];
          uf[uu][p][1] = up[SEQ];
        }
      const int krow = tt * 16 + kl, kch = g << 3;
      bf16x8 kh00 = *(bf16x8*)&KsH[0][krow][kch], kh01 = *(bf16x8*)&KsH[0][krow][kch + 32];
      bf16x8 kb00 = *(bf16x8*)&KsL[0][krow][kch], kb01 = *(bf16x8*)&KsL[0][krow][kch + 32];
      bf16x8 kh10 = *(bf16x8*)&KsH[1][krow][kch], kh11 = *(bf16x8*)&KsH[1][krow][kch + 32];
      bf16x8 kb10 = *(bf16x8*)&KsL[1][krow][kch], kb11 = *(bf16x8*)&KsL[1][krow][kch + 32];
      f32x4 a0 = {0.f, 0.f, 0.f, 0.f}, a1 = {0.f, 0.f, 0.f, 0.f};
      a0 = mfma_bf16(qh[0][0], kh00, a0);  a1 = mfma_bf16(qh[1][0], kh10, a1);
      a0 = mfma_bf16(qh[0][1], kh01, a0);  a1 = mfma_bf16(qh[1][1], kh11, a1);
      a0 = mfma_bf16(qh[0][0], kb00, a0);  a1 = mfma_bf16(qh[1][0], kb10, a1);
      a0 = mfma_bf16(qh[0][1], kb01, a0);  a1 = mfma_bf16(qh[1][1], kb11, a1);
      a0 = mfma_bf16(qo[0][0], kh00, a0);  a1 = mfma_bf16(qo[1][0], kh10, a1);
      a0 = mfma_bf16(qo[0][1], kh01, a0);  a1 = mfma_bf16(qo[1][1], kh11, a1);
#pragma unroll
      for (int p = 0; p < 2; ++p) {
        float ub0x = bub[0], ub0y = bub[0], ub1x = bub[1], ub1y = bub[1];
#pragma unroll
        for (int uu = 0; uu < UE; ++uu) {
          const float flo = uf[uu][p][0];
          const float fhi = uf[uu][p][1];
          ub0x = fmaf(wu_[0][uu], flo, ub0x); ub0y = fmaf(wu_[0][uu], fhi, ub0y);
          ub1x = fmaf(wu_[1][uu], flo, ub1x); ub1y = fmaf(wu_[1][uu], fhi, ub1y);
        }
        const unsigned char m0 = ms[tt * 16 + kl][qb + 2 * p];
        const unsigned char m1 = ms[tt * 16 + kl][qb + 2 * p + 1];
        u16 e00 = m0 ? (u16)0 : f2bf(__expf(a0[2 * p] * QKSCALE + ub0x));
        u16 e01 = m1 ? (u16)0 : f2bf(__expf(a0[2 * p + 1] * QKSCALE + ub0y));
        u16 e10 = m0 ? (u16)0 : f2bf(__expf(a1[2 * p] * QKSCALE + ub1x));
        u16 e11 = m1 ? (u16)0 : f2bf(__expf(a1[2 * p + 1] * QKSCALE + ub1y));
        TrB[w][0][(g << 2) + 2 * p][tt * 16 + kl]     = e00;
        TrB[w][0][(g << 2) + 2 * p + 1][tt * 16 + kl] = e01;
        TrB[w][1][(g << 2) + 2 * p][tt * 16 + kl]     = e10;
        TrB[w][1][(g << 2) + 2 * p + 1][tt * 16 + kl] = e11;
        esum[0][2 * p]     += bf2f(e00);
        esum[0][2 * p + 1] += bf2f(e01);
        esum[1][2 * p]     += bf2f(e10);
        esum[1][2 * p + 1] += bf2f(e11);
      }
    }
    // same-wave flush: 2x bf16x8 per head -> full 64B lines (4 lanes/line)
#pragma unroll
    for (int h2 = 0; h2 < 2; ++h2) {
      bf16x8 v0 = *(bf16x8*)&TrB[w][h2][rr][cg];
      bf16x8 v1 = *(bf16x8*)&TrB[w][h2][rr][cg + 8];
      u16* pp = praw + ((size_t)((b * NH + h0 + h2) * SEQ + q0 + 16 * w + rr)) * 2048 + 1024 + k0 + cg;
      *(bf16x8*)pp = v0;
      *(bf16x8*)(pp + 8) = v1;
    }
#pragma unroll
    for (int h2 = 0; h2 < 2; ++h2)
#pragma unroll
      for (int r = 0; r < 4; ++r) {
#pragma unroll
        for (int o = 1; o <= 8; o <<= 1) esum[h2][r] += __shfl_xor(esum[h2][r], o);
      }
    if (kl == 0) {
#pragma unroll
      for (int h2 = 0; h2 < 2; ++h2)
#pragma unroll
        for (int r = 0; r < 4; ++r)
          sums[((size_t)(b * NH + h0 + h2) * SEQ + q0 + qb + r) * 16 + kt] = esum[h2][r];
    }
  }
}

// ---------------- K3: normalize-write + PV (bf16 praw, no exp) ----------------
__global__ __launch_bounds__(256, 4) void pv_softmax_kernel(
    float* attn, const u16* __restrict__ Vt,
    const float* __restrict__ sums, u16* __restrict__ ctx) {
  const int qt = blockIdx.x, bh = blockIdx.y;
  const int q0 = qt * 64;
  __shared__ u16 Pl[64][72], Vs[64][72];
  __shared__ float invl[64];
  const int t = threadIdx.x, w = t >> 6, l = t & 63;
  const int row = t >> 2, cc = (t & 3) * 16;

  float S = 0.f;
  {
    const float* sp = sums + ((size_t)bh * SEQ + q0 + row) * 16 + (t & 3) * 4;
#pragma unroll
    for (int j = 0; j < 4; ++j) S += sp[j];
#pragma unroll
    for (int o = 1; o <= 2; o <<= 1) S += __shfl_xor(S, o);
  }
  const float inv = 1.0f / S;
  if ((t & 3) == 0) invl[row] = inv;

  const u16* prow = (const u16*)attn + ((size_t)(bh * SEQ + q0 + row)) * 2048 + 1024;
  float* arow = attn + ((size_t)(bh * SEQ + q0 + row)) * SEQ;
  const u16* vrow = Vt + ((size_t)bh * HD + row) * SEQ + cc;

  const int wr = (w >> 1) * 32, wc = (w & 1) * 32;
  f32x4 acc[2][2] = {};
  bf16x8 pa = *(const bf16x8*)&prow[cc], pb = *(const bf16x8*)&prow[cc + 8];
  bf16x8 vb0 = *(const bf16x8*)vrow, vb1 = *(const bf16x8*)(vrow + 8);

  for (int k0 = 0; k0 < SEQ; k0 += 64) {
    float* ap = arow + k0 + cc;
    {
      float4 o0, o1, o2, o3;
      o0.x = bf2f((u16)pa[0]) * inv; o0.y = bf2f((u16)pa[1]) * inv;
      o0.z = bf2f((u16)pa[2]) * inv; o0.w = bf2f((u16)pa[3]) * inv;
      o1.x = bf2f((u16)pa[4]) * inv; o1.y = bf2f((u16)pa[5]) * inv;
      o1.z = bf2f((u16)pa[6]) * inv; o1.w = bf2f((u16)pa[7]) * inv;
      o2.x = bf2f((u16)pb[0]) * inv; o2.y = bf2f((u16)pb[1]) * inv;
      o2.z = bf2f((u16)pb[2]) * inv; o2.w = bf2f((u16)pb[3]) * inv;
      o3.x = bf2f((u16)pb[4]) * inv; o3.y = bf2f((u16)pb[5]) * inv;
      o3.z = bf2f((u16)pb[6]) * inv; o3.w = bf2f((u16)pb[7]) * inv;
      ((float4*)ap)[0] = o0; ((float4*)ap)[1] = o1;
      ((float4*)ap)[2] = o2; ((float4*)ap)[3] = o3;
    }
    *(bf16x8*)&Pl[row][cc] = pa;
    *(bf16x8*)&Pl[row][cc + 8] = pb;
    *(bf16x8*)&Vs[row][cc] = vb0;
    *(bf16x8*)&Vs[row][cc + 8] = vb1;

    if (k0 + 64 < SEQ) {
      pa = *(const bf16x8*)&prow[k0 + 64 + cc];
      pb = *(const bf16x8*)&prow[k0 + 64 + cc + 8];
      vb0 = *(const bf16x8*)(vrow + k0 + 64);
      vb1 = *(const bf16x8*)(vrow + k0 + 72);
    }
    __syncthreads();
#pragma unroll
    for (int kb = 0; kb < 2; ++kb) {
      const int kch = kb * 32 + ((l >> 4) << 3);
      bf16x8 a0 = *(bf16x8*)&Pl[wr + (l & 15)][kch];
      bf16x8 a1 = *(bf16x8*)&Pl[wr + 16 + (l & 15)][kch];
      bf16x8 b0 = *(bf16x8*)&Vs[wc + (l & 15)][kch];
      bf16x8 b1 = *(bf16x8*)&Vs[wc + 16 + (l & 15)][kch];
      acc[0][0] = mfma_bf16(a0, b0, acc[0][0]);
      acc[0][1] = mfma_bf16(a0, b1, acc[0][1]);
      acc[1][0] = mfma_bf16(a1, b0, acc[1][0]);
      acc[1][1] = mfma_bf16(a1, b1, acc[1][1]);
    }
    __syncthreads();
  }
  const int b = bh >> 3, h = bh & 7;
#pragma unroll
  for (int i = 0; i < 2; ++i)
#pragma unroll
    for (int j = 0; j < 2; ++j) {
      const int d = h * HD + wc + 16 * j + (l & 15);
#pragma unroll
      for (int r = 0; r < 4; ++r) {
        const int ql_ = wr + 16 * i + ((l >> 4) << 2) + r;
        ctx[((size_t)(b * SEQ + q0 + ql_)) * EMB + d] = f2bf(acc[i][j][r] * invl[ql_]);
      }
    }
}

// ---------------- K4: out = ctx(bf16) @ Wo^T(hi/lo) + bo ----------------
__global__ __launch_bounds__(256, 2) void oproj_kernel(
    const u16* __restrict__ ctx,
    const u16* __restrict__ WoH, const u16* __restrict__ WoL,
    const float* __restrict__ bo, float* __restrict__ out) {
  const int mt = blockIdx.x, ct = blockIdx.y;
  const int m0 = mt * 64, c0 = ct * 64;
  __shared__ u16 AH[64][40], BH[64][40], BL[64][40];
  const int t = threadIdx.x, w = t >> 6, l = t & 63;
  const int wr = (w >> 1) * 32, wc = (w & 1) * 32;
  f32x4 acc[2][2] = {};
  const int srow = t >> 2, sc = (t & 3) * 8;
  for (int e0 = 0; e0 < EMB; e0 += 32) {
    *(bf16x8*)&AH[srow][sc] = *(const bf16x8*)&ctx[(size_t)(m0 + srow) * EMB + e0 + sc];
    *(bf16x8*)&BH[srow][sc] = *(const bf16x8*)&WoH[(size_t)(c0 + srow) * EMB + e0 + sc];
    *(bf16x8*)&BL[srow][sc] = *(const bf16x8*)&WoL[(size_t)(c0 + srow) * EMB + e0 + sc];
    __syncthreads();
    const int ar = l & 15, ach = (l >> 4) << 3;
    bf16x8 ah0 = *(bf16x8*)&AH[wr + ar][ach],      ah1 = *(bf16x8*)&AH[wr + 16 + ar][ach];
    bf16x8 bh0 = *(bf16x8*)&BH[wc + ar][ach],      bh1 = *(bf16x8*)&BH[wc + 16 + ar][ach];
    bf16x8 bl0 = *(bf16x8*)&BL[wc + ar][ach],      bl1 = *(bf16x8*)&BL[wc + 16 + ar][ach];
    acc[0][0] = mfma_bf16(ah0, bh0, acc[0][0]); acc[0][0] = mfma_bf16(ah0, bl0, acc[0][0]);
    acc[0][1] = mfma_bf16(ah0, bh1, acc[0][1]); acc[0][1] = mfma_bf16(ah0, bl1, acc[0][1]);
    acc[1][0] = mfma_bf16(ah1, bh0, acc[1][0]); acc[1][0] = mfma_bf16(ah1, bl0, acc[1][0]);
    acc[1][1] = mfma_bf16(ah1, bh1, acc[1][1]); acc[1][1] = mfma_bf16(ah1, bl1, acc[1][1]);
    __syncthreads();
  }
#pragma unroll
  for (int i = 0; i < 2; ++i)
#pragma unroll
    for (int j = 0; j < 2; ++j) {
      const int col = c0 + wc + 16 * j + (l & 15);
      const float bias = bo[col];
#pragma unroll
      for (int r = 0; r < 4; ++r) {
        const int m = m0 + wr + 16 * i + ((l >> 4) << 2) + r;
        out[(size_t)m * EMB + col] = acc[i][j][r] + bias;
      }
    }
}

extern "C" void kernel_launch(void* const* d_in, const int* in_sizes, int n_in,
                              void* d_out, int out_size, void* d_ws, size_t ws_size,
                              hipStream_t stream) {
  const float* x = (const float*)d_in[0];
  const float* u = (const float*)d_in[1];
  const int* umask = (const int*)d_in[2];
  const float* Wq = (const float*)d_in[3];
  const float* Wk = (const float*)d_in[4];
  const float* Wv = (const float*)d_in[5];
  const float* Wu = (const float*)d_in[6];
  const float* bu = (const float*)d_in[7];
  const float* Wo = (const float*)d_in[8];
  const float* bo = (const float*)d_in[9];

  float* out = (float*)d_out;
  float* attn = out + (size_t)BSZ * SEQ * EMB;

  const size_t per = (size_t)BSZ * NH * SEQ * HD;  // 4,194,304
  u16* ws = (u16*)d_ws;
  u16* Qhi = ws;
  u16* Qlo = Qhi + per;
  u16* Khi = Qlo + per;
  u16* Klo = Khi + per;
  u16* Vt = Klo + per;
  u16* ctx = Vt + per;
  float* sums = (float*)(ctx + per);               // 4.19MB
  u16* Wsp = (u16*)(sums + (size_t)BSZ * NH * SEQ * 16);
  // ws total: 58.7 MB (proven envelope)

  u16* Xhi = (u16*)attn;
  u16* Xlo = Xhi + (size_t)BSZ * SEQ * EMB;

  const int wn4 = 262144 / 4;
  split4_kernel<<<dim3(wn4 / 256, 4), 256, 0, stream>>>(Wq, Wk, Wv, Wo, Wsp, wn4);
  const int xn4 = (int)((size_t)BSZ * SEQ * EMB / 4);  // 1,048,576
  split_kernel<<<dim3(xn4 / 256), 256, 0, stream>>>(x, Xhi, Xlo, xn4);

  qkv_mfma_kernel<<<dim3(128, 8, 3), 256, 0, stream>>>(Xhi, Xlo, Wsp, Qhi, Qlo, Khi, Klo, Vt);
  scores_kernel<<<dim3(16, 16, 8), 256, 0, stream>>>(Qhi, Qlo, Khi, Klo, u, umask, Wu, bu,
                                                     (u16*)attn, sums);
  pv_softmax_kernel<<<dim3(16, 64), 256, 0, stream>>>(attn, Vt, sums, ctx);
  oproj_kernel<<<dim3(128, 8), 256, 0, stream>>>(ctx, Wsp + 3 * 524288, Wsp + 3 * 524288 + 262144, bo, out);
}